// Round 11
// baseline (45.419 us; speedup 1.0000x reference)
//
#include <hip/hip_runtime.h>
#include <stdint.h>

#define BATCH 128
#define MAXN 1024
#define NF 9
#define DIM 256
#define NCLS 10

// Combined-table sections (rows of 256):
#define BASE1 119
#define BASE2 179
#define BASE3 299
#define QROWS 443

#define TBLK 114                      // table-prep blocks (3 cls + 111 Q)
#define PACKBLK (BATCH * MAXN / 256)  // 512 index-pack blocks

#define NSL 8           // column slices
#define SCOL 32         // f32 columns per slice
#define SLICE_U4 3544   // 443*32*4B / 16B per uint4

typedef __attribute__((ext_vector_type(4))) float f32x4;

// ---------------------------------------------------------------------------
// Prep: 114 table blocks + 512 index-pack blocks.
//  Qf written SLICE-MAJOR f32: Qf[slice][row][col32] so main stages one
//  56.7KB f32 slice contiguously into LDS (NO bf16 unpack in the hot loop —
//  the unpack was ~16 of the ~40 issue-ops per 16B stored, the round-10
//  VALU-issue bottleneck).
//  clsT[c][o] f32; jpack[node] = int4 of 4 combined-table rows.
// ---------------------------------------------------------------------------
__global__ __launch_bounds__(256) void prep_kernel(
    const float* __restrict__ rxn_emb, const float* __restrict__ lin_w,
    const float* __restrict__ lin_b, const float* __restrict__ atom_emb,
    const int* __restrict__ node_feat,
    float* __restrict__ Qf, float* __restrict__ clsT, int4* __restrict__ jpack)
{
  const int bid = blockIdx.x;
  const int t = threadIdx.x;

  if (bid >= TBLK) {  // ---- index-pack path ----
    const int node = (bid - TBLK) * 256 + t;
    const int* p = node_feat + (size_t)node * NF;
    int4 jv;
    jv.x = p[0];
    jv.y = BASE1 + p[1] * 12 + p[2];
    jv.z = BASE2 + p[3] * 10 + p[4];
    jv.w = BASE3 + ((p[5] * 6 + p[6]) * 2 + p[7]) * 2 + p[8];
    jpack[node] = jv;
    return;
  }

  // ---- table path: 4 rows/block, one W sweep amortized ----
  __shared__ float S[4][DIM];
  const bool isCls = bid < 3;
  const int row0 = isCls ? bid * 4 : (bid - 3) * 4;
  const int rmax = isCls ? NCLS : QROWS;
  const int nrows = (rmax - row0 < 4) ? (rmax - row0) : 4;

#pragma unroll
  for (int r = 0; r < 4; ++r) {
    float v = 0.f;
    if (r < nrows) {
      const int q = row0 + r;
      if (isCls) {
        v = rxn_emb[q * DIM + t];
      } else if (q < BASE1) {
        v = atom_emb[q * DIM + t];
      } else if (q < BASE2) {
        int x = q - BASE1;
        v = atom_emb[(119 + x / 12) * DIM + t] + atom_emb[(124 + x % 12) * DIM + t];
      } else if (q < BASE3) {
        int x = q - BASE2;
        v = atom_emb[(136 + x / 10) * DIM + t] + atom_emb[(148 + x % 10) * DIM + t];
      } else {
        int x = q - BASE3;
        int i8 = x & 1, i7 = (x >> 1) & 1, y = x >> 2;
        v = atom_emb[(158 + y / 6) * DIM + t] + atom_emb[(164 + y % 6) * DIM + t]
          + atom_emb[(170 + i7) * DIM + t] + atom_emb[(172 + i8) * DIM + t];
      }
    }
    S[r][t] = v;
  }
  __syncthreads();

  const float* wrow = lin_w + (size_t)t * 2 * DIM + (isCls ? DIM : 0);
  const float init = isCls ? lin_b[t] : 0.f;
  float a0 = init, a1 = init, a2 = init, a3 = init;
#pragma unroll 4
  for (int d = 0; d < DIM; d += 4) {
    float4 w4 = *(const float4*)(wrow + d);
    a0 += w4.x * S[0][d] + w4.y * S[0][d + 1] + w4.z * S[0][d + 2] + w4.w * S[0][d + 3];
    a1 += w4.x * S[1][d] + w4.y * S[1][d + 1] + w4.z * S[1][d + 2] + w4.w * S[1][d + 3];
    a2 += w4.x * S[2][d] + w4.y * S[2][d + 1] + w4.z * S[2][d + 2] + w4.w * S[2][d + 3];
    a3 += w4.x * S[3][d] + w4.y * S[3][d + 1] + w4.z * S[3][d + 2] + w4.w * S[3][d + 3];
  }
  if (isCls) {
    if (0 < nrows) clsT[(row0 + 0) * DIM + t] = a0;
    if (1 < nrows) clsT[(row0 + 1) * DIM + t] = a1;
    if (2 < nrows) clsT[(row0 + 2) * DIM + t] = a2;
    if (3 < nrows) clsT[(row0 + 3) * DIM + t] = a3;
  } else {
    // slice-major f32: s = t>>5 (0..7), c = t&31
    const int s = t >> 5, c = t & 31;
    float* dst = Qf + (size_t)s * QROWS * SCOL + c;
    if (0 < nrows) dst[(row0 + 0) * SCOL] = a0;
    if (1 < nrows) dst[(row0 + 1) * SCOL] = a1;
    if (2 < nrows) dst[(row0 + 2) * SCOL] = a2;
    if (3 < nrows) dst[(row0 + 3) * SCOL] = a3;
  }
}

// ---------------------------------------------------------------------------
// Main: 4096 blocks (8 slices x 128 batches x 4 node-quarters) x 1024 thr.
// SINGLE CHANGE vs round 10: LDS table is f32 (no bf16 unpack). Per 16B
// stored: 4 ds_read_b128 + ~13 adds + 1 store (~20 wave-instrs, was ~40).
// LDS reads conflict-free: each 8-lane group's 4xb128 covers all 32 banks
// exactly once. 56.7KB LDS -> 2 blocks/CU, 32 waves/CU.
// Lane: nd = lane>>3 (node sub-idx 0..7), c = lane&7 (col quad); wave owns
// 16 nodes in 2 passes. Masked quarters/waves pure-fill the class row.
// ---------------------------------------------------------------------------
__global__ __launch_bounds__(1024) void main_kernel(
    const int4* __restrict__ jpack, const int* __restrict__ num_nodes,
    const int* __restrict__ rxn_class,
    const float* __restrict__ Qf, const float* __restrict__ clsT,
    float* __restrict__ out)
{
  __shared__ float Ls[QROWS * SCOL];  // 56704 B

  const int tid = threadIdx.x;
  const int bid = blockIdx.x;
  const int s = bid & 7;                 // slice
  const int b = (bid >> 3) & 127;        // batch
  const int q = bid >> 10;               // node quarter (0..3)
  const int n0_blk = q * 256;
  const int nn = num_nodes[b];
  const int cls = rxn_class[b];
  const f32x4* __restrict__ clsT4 = (const f32x4*)clsT;
  f32x4* __restrict__ out4 = (f32x4*)out;

  if (n0_blk >= nn) {
    // fully masked quarter: fill 256 nodes x 32 cols with class row
    const f32x4 cf = clsT4[cls * 64 + s * 8 + (tid & 7)];
    const size_t base = (size_t)(b * MAXN + n0_blk) * 64 + s * 8;
#pragma unroll
    for (int k = 0; k < 2; ++k) {
      const int idx = tid + k * 1024;          // 0..2047
      const int node = idx >> 3, c4 = idx & 7;
      out4[base + (size_t)node * 64 + c4] = cf;
    }
    return;
  }

  // stage f32 slice into LDS (contiguous, uint4 granules)
  {
    const uint4* __restrict__ src = (const uint4*)(Qf + (size_t)s * QROWS * SCOL);
    uint4* dst = (uint4*)Ls;
    for (int i = tid; i < SLICE_U4; i += 1024) dst[i] = src[i];
  }
  __syncthreads();

  const int w = __builtin_amdgcn_readfirstlane(tid >> 6);  // wave 0..15
  const int lane = tid & 63;
  const int nd = lane >> 3;     // node sub-index 0..7
  const int c = lane & 7;       // col quad 0..7
  const int n0 = n0_blk + w * 16;

  const f32x4 cf = clsT4[cls * 64 + s * 8 + c];
  const f32x4* __restrict__ Lp = (const f32x4*)Ls;   // row*8 + c
  const int4* __restrict__ jp = jpack + (size_t)b * MAXN;
  const size_t obase = (size_t)(b * MAXN) * 64 + s * 8 + c;

  if (n0 >= nn) {  // masked wave: fill its 16 nodes
#pragma unroll
    for (int p = 0; p < 2; ++p) {
      const int n = n0 + p * 8 + nd;
      out4[obase + (size_t)n * 64] = cf;
    }
    return;
  }

  if (n0 + 16 <= nn) {  // fully valid wave
#pragma unroll
    for (int p = 0; p < 2; ++p) {
      const int n = n0 + p * 8 + nd;
      const int4 jv = jp[n];
      const f32x4 v0 = Lp[jv.x * 8 + c];
      const f32x4 v1 = Lp[jv.y * 8 + c];
      const f32x4 v2 = Lp[jv.z * 8 + c];
      const f32x4 v3 = Lp[jv.w * 8 + c];
      out4[obase + (size_t)n * 64] = cf + ((v0 + v1) + (v2 + v3));
    }
    return;
  }

  // partial wave: branchless per-lane mask
#pragma unroll
  for (int p = 0; p < 2; ++p) {
    const int n = n0 + p * 8 + nd;
    const int4 jv = jp[n];
    const f32x4 v0 = Lp[jv.x * 8 + c];
    const f32x4 v1 = Lp[jv.y * 8 + c];
    const f32x4 v2 = Lp[jv.z * 8 + c];
    const f32x4 v3 = Lp[jv.w * 8 + c];
    const float m = (n < nn) ? 1.f : 0.f;
    out4[obase + (size_t)n * 64] = cf + m * ((v0 + v1) + (v2 + v3));
  }
}

extern "C" void kernel_launch(void* const* d_in, const int* in_sizes, int n_in,
                              void* d_out, int out_size, void* d_ws, size_t ws_size,
                              hipStream_t stream) {
  const int* node_feat = (const int*)d_in[0];
  const int* num_nodes = (const int*)d_in[1];
  const int* rxn_class = (const int*)d_in[2];
  const float* atom_emb = (const float*)d_in[3];
  const float* rxn_emb = (const float*)d_in[4];
  const float* lin_w = (const float*)d_in[5];
  const float* lin_b = (const float*)d_in[6];
  float* outp = (float*)d_out;

  // workspace: Qf slice-major f32 (453632 B) | clsT (10240 B) | jpack @512KB
  float* Qf = (float*)d_ws;
  float* clsT = (float*)((char*)d_ws + QROWS * SCOL * NSL * sizeof(float));
  int4* jpack = (int4*)((char*)d_ws + 524288);

  prep_kernel<<<TBLK + PACKBLK, 256, 0, stream>>>(rxn_emb, lin_w, lin_b,
                                                  atom_emb, node_feat,
                                                  Qf, clsT, jpack);
  main_kernel<<<NSL * BATCH * 4, 1024, 0, stream>>>(jpack, num_nodes, rxn_class,
                                                    Qf, clsT, outp);
}

// Round 12
// 43.333 us; speedup vs baseline: 1.0481x; 1.0481x over previous
//
#include <hip/hip_runtime.h>
#include <stdint.h>

#define BATCH 128
#define MAXN 1024
#define NF 9
#define DIM 256
#define NCLS 10

// Combined-table sections (rows of 256):
#define BASE1 119
#define BASE2 179
#define BASE3 299
#define QROWS 443

#define TBLK 114                      // table-prep blocks (3 cls + 111 Q)
#define PACKBLK (BATCH * MAXN / 256)  // 512 index-pack blocks

typedef __attribute__((ext_vector_type(4))) float f32x4;
typedef __attribute__((ext_vector_type(2))) uint32_t u32x2;

__device__ __forceinline__ ushort f32_to_bf16_rne(float x) {
  uint32_t u = __float_as_uint(x);
  u += 0x7fffu + ((u >> 16) & 1u);
  return (ushort)(u >> 16);
}

__device__ __forceinline__ f32x4 bf4_to_f32x4(u32x2 v) {
  f32x4 r;
  r.x = __uint_as_float(v.x << 16);
  r.y = __uint_as_float(v.x & 0xffff0000u);
  r.z = __uint_as_float(v.y << 16);
  r.w = __uint_as_float(v.y & 0xffff0000u);
  return r;
}

// ---------------------------------------------------------------------------
// Prep (r8's proven shape): 114 table blocks + 512 index-pack blocks.
//  bid in [0,3):     clsT[c][o] f32 = lin_b[o] + W2[o]·rxn_emb[c]
//  bid in [3,114):   Qb[q][o] bf16 = W1[o]·S_q  (row-major 443x256)
//  bid in [114,626): jpack[node] = int4 of the 4 combined-table rows
// ---------------------------------------------------------------------------
__global__ __launch_bounds__(256) void prep_kernel(
    const float* __restrict__ rxn_emb, const float* __restrict__ lin_w,
    const float* __restrict__ lin_b, const float* __restrict__ atom_emb,
    const int* __restrict__ node_feat,
    ushort* __restrict__ Qb, float* __restrict__ clsT, int4* __restrict__ jpack)
{
  const int bid = blockIdx.x;
  const int t = threadIdx.x;

  if (bid >= TBLK) {  // ---- index-pack path ----
    const int node = (bid - TBLK) * 256 + t;
    const int* p = node_feat + (size_t)node * NF;
    int4 jv;
    jv.x = p[0];
    jv.y = BASE1 + p[1] * 12 + p[2];
    jv.z = BASE2 + p[3] * 10 + p[4];
    jv.w = BASE3 + ((p[5] * 6 + p[6]) * 2 + p[7]) * 2 + p[8];
    jpack[node] = jv;
    return;
  }

  // ---- table path: 4 rows/block, one W sweep amortized ----
  __shared__ float S[4][DIM];
  const bool isCls = bid < 3;
  const int row0 = isCls ? bid * 4 : (bid - 3) * 4;
  const int rmax = isCls ? NCLS : QROWS;
  const int nrows = (rmax - row0 < 4) ? (rmax - row0) : 4;

#pragma unroll
  for (int r = 0; r < 4; ++r) {
    float v = 0.f;
    if (r < nrows) {
      const int q = row0 + r;
      if (isCls) {
        v = rxn_emb[q * DIM + t];
      } else if (q < BASE1) {
        v = atom_emb[q * DIM + t];
      } else if (q < BASE2) {
        int x = q - BASE1;
        v = atom_emb[(119 + x / 12) * DIM + t] + atom_emb[(124 + x % 12) * DIM + t];
      } else if (q < BASE3) {
        int x = q - BASE2;
        v = atom_emb[(136 + x / 10) * DIM + t] + atom_emb[(148 + x % 10) * DIM + t];
      } else {
        int x = q - BASE3;
        int i8 = x & 1, i7 = (x >> 1) & 1, y = x >> 2;
        v = atom_emb[(158 + y / 6) * DIM + t] + atom_emb[(164 + y % 6) * DIM + t]
          + atom_emb[(170 + i7) * DIM + t] + atom_emb[(172 + i8) * DIM + t];
      }
    }
    S[r][t] = v;
  }
  __syncthreads();

  const float* wrow = lin_w + (size_t)t * 2 * DIM + (isCls ? DIM : 0);
  const float init = isCls ? lin_b[t] : 0.f;
  float a0 = init, a1 = init, a2 = init, a3 = init;
#pragma unroll 4
  for (int d = 0; d < DIM; d += 4) {
    float4 w4 = *(const float4*)(wrow + d);
    a0 += w4.x * S[0][d] + w4.y * S[0][d + 1] + w4.z * S[0][d + 2] + w4.w * S[0][d + 3];
    a1 += w4.x * S[1][d] + w4.y * S[1][d + 1] + w4.z * S[1][d + 2] + w4.w * S[1][d + 3];
    a2 += w4.x * S[2][d] + w4.y * S[2][d + 1] + w4.z * S[2][d + 2] + w4.w * S[2][d + 3];
    a3 += w4.x * S[3][d] + w4.y * S[3][d + 1] + w4.z * S[3][d + 2] + w4.w * S[3][d + 3];
  }
  if (isCls) {
    if (0 < nrows) clsT[(row0 + 0) * DIM + t] = a0;
    if (1 < nrows) clsT[(row0 + 1) * DIM + t] = a1;
    if (2 < nrows) clsT[(row0 + 2) * DIM + t] = a2;
    if (3 < nrows) clsT[(row0 + 3) * DIM + t] = a3;
  } else {
    if (0 < nrows) Qb[(row0 + 0) * DIM + t] = f32_to_bf16_rne(a0);
    if (1 < nrows) Qb[(row0 + 1) * DIM + t] = f32_to_bf16_rne(a1);
    if (2 < nrows) Qb[(row0 + 2) * DIM + t] = f32_to_bf16_rne(a2);
    if (3 < nrows) Qb[(row0 + 3) * DIM + t] = f32_to_bf16_rne(a3);
  }
}

// ---------------------------------------------------------------------------
// Main: 4096 blocks x 256 threads; ONE 8-node strip per wave, PHASE-SPLIT:
//   phase 1: all jpack loads (wave-uniform -> s_load) + all 32 gathers,
//            accumulate into res[8] registers. ONE vmcnt wait, no stores yet.
//   sched_barrier(0): hard fence — no store moves up, no load moves down.
//   phase 2: 8 back-to-back f32x4 stores (1024B/wave, coalesced), then end.
// Rationale: stores share the in-order vmcnt queue with loads; every prior
// variant had a gather-wait BETWEEN stores, draining the store queue to
// write-ack (~500-700cyc) each iteration — the common mechanism behind 8
// null levers. Fill kernels (6.7 TB/s at 3 waves/CU) have zero waitcnts in
// their store loop. This kernel's store stream has zero waitcnts after it.
// ---------------------------------------------------------------------------
__global__ __launch_bounds__(256) void main_kernel(
    const int4* __restrict__ jpack, const int* __restrict__ num_nodes,
    const int* __restrict__ rxn_class,
    const ushort* __restrict__ Qb, const float* __restrict__ clsT,
    float* __restrict__ out)
{
  const int tid = threadIdx.x;
  const int lane = tid & 63;
  const int w = __builtin_amdgcn_readfirstlane(tid >> 6);
  const int wid = blockIdx.x * 4 + w;   // 0..16383
  const int b = wid >> 7;               // 128 waves per batch
  const int n0 = (wid & 127) << 3;      // 8 nodes per wave
  const int nn = num_nodes[b];

  const f32x4 cf = ((const f32x4*)clsT)[rxn_class[b] * 64 + lane];
  f32x4* __restrict__ outp = (f32x4*)out + ((size_t)(b * MAXN + n0)) * 64 + lane;

  if (n0 >= nn) {  // fully masked strip: pure store stream
#pragma unroll
    for (int i = 0; i < 8; ++i)
      outp[i * 64] = cf;
    return;
  }

  const int4* __restrict__ jp = jpack + (size_t)b * MAXN + n0;
  const u32x2* __restrict__ Q2 = (const u32x2*)Qb;

  f32x4 res[8];
  if (n0 + 8 <= nn) {  // fully valid strip
#pragma unroll
    for (int i = 0; i < 8; ++i) {
      const int4 jv = jp[i];
      const u32x2 v0 = Q2[jv.x * 64 + lane];
      const u32x2 v1 = Q2[jv.y * 64 + lane];
      const u32x2 v2 = Q2[jv.z * 64 + lane];
      const u32x2 v3 = Q2[jv.w * 64 + lane];
      res[i] = cf + ((bf4_to_f32x4(v0) + bf4_to_f32x4(v1))
                   + (bf4_to_f32x4(v2) + bf4_to_f32x4(v3)));
    }
  } else {  // partial strip (<=1 per batch): branchless float-mask
#pragma unroll
    for (int i = 0; i < 8; ++i) {
      const int4 jv = jp[i];
      const u32x2 v0 = Q2[jv.x * 64 + lane];
      const u32x2 v1 = Q2[jv.y * 64 + lane];
      const u32x2 v2 = Q2[jv.z * 64 + lane];
      const u32x2 v3 = Q2[jv.w * 64 + lane];
      const float m = (n0 + i < nn) ? 1.f : 0.f;
      res[i] = cf + m * ((bf4_to_f32x4(v0) + bf4_to_f32x4(v1))
                       + (bf4_to_f32x4(v2) + bf4_to_f32x4(v3)));
    }
  }

  __builtin_amdgcn_sched_barrier(0);  // fence: stores below, loads above

#pragma unroll
  for (int i = 0; i < 8; ++i)
    outp[i * 64] = res[i];
}

extern "C" void kernel_launch(void* const* d_in, const int* in_sizes, int n_in,
                              void* d_out, int out_size, void* d_ws, size_t ws_size,
                              hipStream_t stream) {
  const int* node_feat = (const int*)d_in[0];
  const int* num_nodes = (const int*)d_in[1];
  const int* rxn_class = (const int*)d_in[2];
  const float* atom_emb = (const float*)d_in[3];
  const float* rxn_emb = (const float*)d_in[4];
  const float* lin_w = (const float*)d_in[5];
  const float* lin_b = (const float*)d_in[6];
  float* outp = (float*)d_out;

  // workspace: Qb row-major bf16 (226816 B) | clsT (10240 B) | jpack @256KB
  ushort* Qb = (ushort*)d_ws;
  float* clsT = (float*)((char*)d_ws + QROWS * DIM * sizeof(ushort));
  int4* jpack = (int4*)((char*)d_ws + 262144);

  prep_kernel<<<TBLK + PACKBLK, 256, 0, stream>>>(rxn_emb, lin_w, lin_b,
                                                  atom_emb, node_feat,
                                                  Qb, clsT, jpack);
  main_kernel<<<4096, 256, 0, stream>>>(jpack, num_nodes, rxn_class,
                                        Qb, clsT, outp);
}